// Round 3
// baseline (543.719 us; speedup 1.0000x reference)
//
#include <hip/hip_runtime.h>

typedef unsigned short ushort_t;
typedef __attribute__((ext_vector_type(8))) short short8;
typedef __attribute__((ext_vector_type(4))) float floatx4;

#define B_ 4
#define T_ 2048
#define C_ 1024
#define H_ 16
#define D_ 64
#define BT_ (B_ * T_)
#define N3C (3 * C_)

// softmax scale * log2(e): use exp2
#define KSC 0.18033688011112042f

__device__ __forceinline__ float bf2f(ushort_t h) {
    return __uint_as_float(((unsigned)h) << 16);
}
__device__ __forceinline__ ushort_t f2bf(float f) {
    unsigned u = __float_as_uint(f);
    u += 0x7FFF + ((u >> 16) & 1);  // round-nearest-even
    return (ushort_t)(u >> 16);
}

__device__ __forceinline__ void gload16(const ushort_t* g, ushort_t* l) {
    __builtin_amdgcn_global_load_lds((const __attribute__((address_space(1))) void*)g,
                                     (__attribute__((address_space(3))) void*)l, 16, 0, 0);
}

// ---------------- dtype probe: fp32 buffer -> |v| small; bf16 misread -> |v|~1e34/NaN ----
__global__ void detect_k(const float* __restrict__ w, int* __restrict__ flag) {
    float f = w[threadIdx.x];                     // 64 threads, 256B read
    bool big = !(fabsf(f) <= 1e20f);              // catches huge AND NaN
    unsigned long long m = __ballot(big);
    if (threadIdx.x == 0) flag[0] = (m != 0ull) ? 1 : 0;
}

// ---------------- x -> bf16 (convert or copy) ----------------
__global__ void convert_x_k(const void* __restrict__ xin, ushort_t* __restrict__ xb,
                            const int* __restrict__ flag) {
    size_t i = ((size_t)blockIdx.x * 256 + threadIdx.x) * 8;
    if (*flag) {
        *(short8*)&xb[i] = *(const short8*)((const ushort_t*)xin + i);
    } else {
        const float* xf = (const float*)xin + i;
        float4 a = *(const float4*)xf;
        float4 b = *(const float4*)(xf + 4);
        short8 o;
        o[0] = (short)f2bf(a.x); o[1] = (short)f2bf(a.y);
        o[2] = (short)f2bf(a.z); o[3] = (short)f2bf(a.w);
        o[4] = (short)f2bf(b.x); o[5] = (short)f2bf(b.y);
        o[6] = (short)f2bf(b.z); o[7] = (short)f2bf(b.w);
        *(short8*)&xb[i] = o;
    }
}

// ---------------- transpose(+convert): in[R][Nc] -> out[Nc][R] bf16 ----------------
__global__ void transpose_k(const void* __restrict__ in, ushort_t* __restrict__ out,
                            int R, int Nc, const int* __restrict__ flag) {
    __shared__ ushort_t t[32][33];
    int fl = *flag;
    const float* inf_ = (const float*)in;
    const ushort_t* inb = (const ushort_t*)in;
    int bc = blockIdx.x * 32;  // col block of in
    int br = blockIdx.y * 32;  // row block of in
    int lx = threadIdx.x & 31, ly = threadIdx.x >> 5;  // ly: 0..7
#pragma unroll
    for (int i = 0; i < 4; ++i) {
        int r = ly + i * 8;
        size_t idx = (size_t)(br + r) * Nc + bc + lx;
        t[r][lx] = fl ? inb[idx] : f2bf(inf_[idx]);
    }
    __syncthreads();
#pragma unroll
    for (int i = 0; i < 4; ++i) {
        int r = ly + i * 8;  // row of out-block (= col of in)
        out[(size_t)(bc + r) * R + br + lx] = t[lx][r];
    }
}

// ---------------- GEMM: C[M][N] = A[M][K] * Bt[N][K] + bias[N] ----------------
// MODE 0: write Cout[M][N] (fp32 or bf16 per flag).
// MODE 1: QKV scatter: col selects q/k/v + (h,d); row = b*T + t; write bf16 [B,H,T,D].
template <int MODE>
__launch_bounds__(256)
__global__ void gemm_bt(const ushort_t* __restrict__ A, const ushort_t* __restrict__ Bt,
                        const void* __restrict__ bias, void* __restrict__ Cout,
                        ushort_t* __restrict__ Qo, ushort_t* __restrict__ Ko,
                        ushort_t* __restrict__ Vo, int M, int N, int K,
                        const int* __restrict__ flag) {
    __shared__ __align__(16) ushort_t Alds[128 * 32];
    __shared__ __align__(16) ushort_t Blds[128 * 32];
    int tid = threadIdx.x;
    int wave = tid >> 6, lane = tid & 63;
    int bm = blockIdx.x * 128, bn = blockIdx.y * 128;
    int wr = (wave >> 1) * 64, wc = (wave & 1) * 64;
    int lm = lane & 15, lk = (lane >> 4) * 8, lq = lane >> 4;

    floatx4 acc[4][4] = {};

    int srow = tid >> 2;            // 0..63
    int scol = (tid & 3) * 8;       // 0,8,16,24
    const ushort_t* Ab = A + (size_t)(bm + srow) * K + scol;
    const ushort_t* Bb = Bt + (size_t)(bn + srow) * K + scol;
    ushort_t* Al0 = &Alds[wave * 512];
    ushort_t* Al1 = &Alds[2048 + wave * 512];
    ushort_t* Bl0 = &Blds[wave * 512];
    ushort_t* Bl1 = &Blds[2048 + wave * 512];
    size_t rowskip = (size_t)64 * K;

    for (int k0 = 0; k0 < K; k0 += 32) {
        __syncthreads();
        gload16(Ab + k0, Al0);
        gload16(Ab + k0 + rowskip, Al1);
        gload16(Bb + k0, Bl0);
        gload16(Bb + k0 + rowskip, Bl1);
        __syncthreads();
        short8 af[4], bf[4];
#pragma unroll
        for (int i = 0; i < 4; ++i)
            af[i] = *(const short8*)&Alds[(wr + i * 16 + lm) * 32 + lk];
#pragma unroll
        for (int i = 0; i < 4; ++i)
            bf[i] = *(const short8*)&Blds[(wc + i * 16 + lm) * 32 + lk];
#pragma unroll
        for (int mi = 0; mi < 4; ++mi)
#pragma unroll
            for (int ni = 0; ni < 4; ++ni)
                acc[mi][ni] = __builtin_amdgcn_mfma_f32_16x16x32_bf16(
                    af[mi], bf[ni], acc[mi][ni], 0, 0, 0);
    }

    int fl = *flag;
#pragma unroll
    for (int mi = 0; mi < 4; ++mi) {
#pragma unroll
        for (int ni = 0; ni < 4; ++ni) {
            int col = bn + wc + ni * 16 + lm;
            float bv = fl ? bf2f(((const ushort_t*)bias)[col]) : ((const float*)bias)[col];
#pragma unroll
            for (int r = 0; r < 4; ++r) {
                int row = bm + wr + mi * 16 + lq * 4 + r;
                float v = acc[mi][ni][r] + bv;
                if (MODE == 0) {
                    if (fl) ((ushort_t*)Cout)[(size_t)row * N + col] = f2bf(v);
                    else    ((float*)Cout)[(size_t)row * N + col] = v;
                } else {
                    int b = row >> 11, t = row & (T_ - 1);
                    int which = col >> 10, c = col & (C_ - 1);
                    int h = c >> 6, d = c & 63;
                    size_t idx = (((size_t)(b * H_ + h)) * T_ + t) * D_ + d;
                    ushort_t bb = f2bf(v);
                    if (which == 0) Qo[idx] = bb;
                    else if (which == 1) Ko[idx] = bb;
                    else Vo[idx] = bb;
                }
            }
        }
    }
}

// ---------------- flash attention, causal ----------------
// grid: (T/64, B*H). Block: 256 = 4 waves; wave w handles Q rows [q0+16w, q0+16w+16).
// Q/K/V layout: [B*H][T][D] bf16. Output written bf16 as [B][T][C].
__launch_bounds__(256)
__global__ void attn_k(const ushort_t* __restrict__ Q, const ushort_t* __restrict__ K,
                       const ushort_t* __restrict__ V, ushort_t* __restrict__ O) {
    __shared__ __align__(16) ushort_t Klds[64 * 72];
    __shared__ __align__(16) ushort_t Vtlds[64 * 72];
    __shared__ __align__(16) ushort_t Plds[4][16 * 72];

    int tid = threadIdx.x, wave = tid >> 6, lane = tid & 63;
    int bh = blockIdx.y;
    int b = bh >> 4, h = bh & 15;
    int q0 = ((int)gridDim.x - 1 - (int)blockIdx.x) * 64;  // heavy blocks first
    int q0w = q0 + wave * 16;
    int lm = lane & 15, lq = lane >> 4;

    const ushort_t* Qp = Q + (size_t)bh * T_ * D_;
    const ushort_t* Kp = K + (size_t)bh * T_ * D_;
    const ushort_t* Vp = V + (size_t)bh * T_ * D_;

    // Q fragments (A-layout: m=lane&15, k=lq*8+j), 2 k-steps of 32 over D=64
    short8 qf0 = *(const short8*)&Qp[(size_t)(q0w + lm) * D_ + lq * 8];
    short8 qf1 = *(const short8*)&Qp[(size_t)(q0w + lm) * D_ + 32 + lq * 8];

    floatx4 oacc[4] = {};
    float mi_[4] = {-__builtin_inff(), -__builtin_inff(), -__builtin_inff(), -__builtin_inff()};
    float li_[4] = {0.f, 0.f, 0.f, 0.f};

    int skv = tid >> 2, sdg = (tid & 3) * 8;      // K staging: (kv row, d group) x2 halves
    int vkv = tid & 63, vd0 = (tid >> 6) * 8;     // V staging: (kv row, d group) x2 halves

    int ntiles = q0 / 64 + 1;
    for (int it = 0; it < ntiles; ++it) {
        int kv0 = it * 64;
        __syncthreads();
        // stage K [kv][d] (rows padded to 72): d in [sdg,sdg+8) and [sdg+32,sdg+40)
        {
            short8 k8a = *(const short8*)&Kp[(size_t)(kv0 + skv) * D_ + sdg];
            short8 k8b = *(const short8*)&Kp[(size_t)(kv0 + skv) * D_ + sdg + 32];
            *(short8*)&Klds[skv * 72 + sdg] = k8a;
            *(short8*)&Klds[skv * 72 + sdg + 32] = k8b;
        }
        // stage V transposed: Vt[d][kv]
#pragma unroll
        for (int half = 0; half < 2; ++half) {
            int d0 = vd0 + half * 32;
            short8 v8 = *(const short8*)&Vp[(size_t)(kv0 + vkv) * D_ + d0];
#pragma unroll
            for (int j = 0; j < 8; ++j)
                Vtlds[(d0 + j) * 72 + vkv] = (ushort_t)v8[j];
        }
        __syncthreads();

        // S = Q K^T  (4 n-tiles of 16 cols)
        floatx4 s[4] = {};
#pragma unroll
        for (int nt = 0; nt < 4; ++nt) {
            short8 kf0 = *(const short8*)&Klds[(nt * 16 + lm) * 72 + lq * 8];
            short8 kf1 = *(const short8*)&Klds[(nt * 16 + lm) * 72 + 32 + lq * 8];
            s[nt] = __builtin_amdgcn_mfma_f32_16x16x32_bf16(qf0, kf0, s[nt], 0, 0, 0);
            s[nt] = __builtin_amdgcn_mfma_f32_16x16x32_bf16(qf1, kf1, s[nt], 0, 0, 0);
        }

        // causal mask (only the last tile can cross the diagonal)
        if (it == ntiles - 1) {
#pragma unroll
            for (int nt = 0; nt < 4; ++nt)
#pragma unroll
                for (int r = 0; r < 4; ++r) {
                    int colg = kv0 + nt * 16 + lm;
                    int rowg = q0w + lq * 4 + r;
                    if (colg > rowg) s[nt][r] = -__builtin_inff();
                }
        }

        // online softmax
        float mnew[4], alpha[4];
#pragma unroll
        for (int r = 0; r < 4; ++r) {
            float mx = fmaxf(fmaxf(s[0][r], s[1][r]), fmaxf(s[2][r], s[3][r]));
#pragma unroll
            for (int off = 1; off < 16; off <<= 1) mx = fmaxf(mx, __shfl_xor(mx, off));
            mnew[r] = fmaxf(mi_[r], mx);
            alpha[r] = exp2f((mi_[r] - mnew[r]) * KSC);
        }
        float rsum[4] = {0.f, 0.f, 0.f, 0.f};
#pragma unroll
        for (int nt = 0; nt < 4; ++nt)
#pragma unroll
            for (int r = 0; r < 4; ++r) {
                float p = exp2f((s[nt][r] - mnew[r]) * KSC);
                rsum[r] += p;
                Plds[wave][(lq * 4 + r) * 72 + nt * 16 + lm] = f2bf(p);
            }
#pragma unroll
        for (int r = 0; r < 4; ++r) {
            float t = rsum[r];
#pragma unroll
            for (int off = 1; off < 16; off <<= 1) t += __shfl_xor(t, off);
            li_[r] = li_[r] * alpha[r] + t;
            mi_[r] = mnew[r];
#pragma unroll
            for (int dt = 0; dt < 4; ++dt) oacc[dt][r] *= alpha[r];
        }

        asm volatile("s_waitcnt lgkmcnt(0)" ::: "memory");  // P write -> P read (same wave)

        // O += P V   (P: A-layout from LDS; V: B-layout from Vt)
        short8 pf0 = *(const short8*)&Plds[wave][lm * 72 + lq * 8];
        short8 pf1 = *(const short8*)&Plds[wave][lm * 72 + 32 + lq * 8];
#pragma unroll
        for (int dt = 0; dt < 4; ++dt) {
            short8 vf0 = *(const short8*)&Vtlds[(dt * 16 + lm) * 72 + lq * 8];
            short8 vf1 = *(const short8*)&Vtlds[(dt * 16 + lm) * 72 + 32 + lq * 8];
            oacc[dt] = __builtin_amdgcn_mfma_f32_16x16x32_bf16(pf0, vf0, oacc[dt], 0, 0, 0);
            oacc[dt] = __builtin_amdgcn_mfma_f32_16x16x32_bf16(pf1, vf1, oacc[dt], 0, 0, 0);
        }
    }

    // epilogue: O /= l, write bf16 to attn_out[b][t][h*64+d]
    ushort_t* Ob = O + ((size_t)b * T_) * C_ + h * D_;
#pragma unroll
    for (int r = 0; r < 4; ++r) {
        float inv = 1.0f / li_[r];
        int rowg = q0w + lq * 4 + r;
#pragma unroll
        for (int dt = 0; dt < 4; ++dt)
            Ob[(size_t)rowg * C_ + dt * 16 + lm] = f2bf(oacc[dt][r] * inv);
    }
}

extern "C" void kernel_launch(void* const* d_in, const int* in_sizes, int n_in,
                              void* d_out, int out_size, void* d_ws, size_t ws_size,
                              hipStream_t stream) {
    const void* x    = d_in[0];
    const void* Wqkv = d_in[1];
    const void* bqkv = d_in[2];
    const void* Wo   = d_in[3];
    const void* bo   = d_in[4];

    int* flag = (int*)d_ws;
    ushort_t* ws = (ushort_t*)d_ws + 8;                    // 16B header
    ushort_t* WqkvT = ws;                                  // [3C][C] bf16
    ushort_t* WoT   = WqkvT + (size_t)N3C * C_;            // [C][C]  bf16
    ushort_t* Xb    = WoT + (size_t)C_ * C_;               // [BT][C] bf16
    ushort_t* Qs    = Xb + (size_t)BT_ * C_;               // [B*H][T][D] bf16
    ushort_t* Ks    = Qs + (size_t)BT_ * C_;
    ushort_t* Vs    = Ks + (size_t)BT_ * C_;
    ushort_t* Attn  = Vs + (size_t)BT_ * C_;               // [B*T][C] bf16

    detect_k<<<1, 64, 0, stream>>>((const float*)Wqkv, flag);
    convert_x_k<<<BT_ * C_ / (256 * 8), 256, 0, stream>>>(x, Xb, flag);
    transpose_k<<<dim3(N3C / 32, C_ / 32), 256, 0, stream>>>(Wqkv, WqkvT, C_, N3C, flag);
    transpose_k<<<dim3(C_ / 32, C_ / 32), 256, 0, stream>>>(Wo, WoT, C_, C_, flag);
    gemm_bt<1><<<dim3(BT_ / 128, N3C / 128), 256, 0, stream>>>(
        Xb, WqkvT, bqkv, nullptr, Qs, Ks, Vs, BT_, N3C, C_, flag);
    attn_k<<<dim3(T_ / 64, B_ * H_), 256, 0, stream>>>(Qs, Ks, Vs, Attn);
    gemm_bt<0><<<dim3(BT_ / 128, C_ / 128), 256, 0, stream>>>(
        Attn, WoT, bo, d_out, nullptr, nullptr, nullptr, BT_, C_, C_, flag);
}

// Round 4
// 499.819 us; speedup vs baseline: 1.0878x; 1.0878x over previous
//
#include <hip/hip_runtime.h>

typedef unsigned short ushort_t;
typedef __attribute__((ext_vector_type(8))) short short8;
typedef __attribute__((ext_vector_type(4))) float floatx4;

#define B_ 4
#define T_ 2048
#define C_ 1024
#define H_ 16
#define D_ 64
#define BT_ (B_ * T_)
#define N3C (3 * C_)

// softmax scale * log2(e): use exp2
#define KSC 0.18033688011112042f

__device__ __forceinline__ float bf2f(ushort_t h) {
    return __uint_as_float(((unsigned)h) << 16);
}
__device__ __forceinline__ ushort_t f2bf(float f) {
    unsigned u = __float_as_uint(f);
    u += 0x7FFF + ((u >> 16) & 1);  // round-nearest-even
    return (ushort_t)(u >> 16);
}

__device__ __forceinline__ void gload16(const ushort_t* g, ushort_t* l) {
    __builtin_amdgcn_global_load_lds((const __attribute__((address_space(1))) void*)g,
                                     (__attribute__((address_space(3))) void*)l, 16, 0, 0);
}

// ---------------- dtype probe: fp32 buffer -> |v| small; bf16 misread -> |v|~1e34/NaN ----
__global__ void detect_k(const float* __restrict__ w, int* __restrict__ flag) {
    float f = w[threadIdx.x];
    bool big = !(fabsf(f) <= 1e20f);
    unsigned long long m = __ballot(big);
    if (threadIdx.x == 0) flag[0] = (m != 0ull) ? 1 : 0;
}

// ---------------- x -> bf16 (convert or copy) ----------------
__global__ void convert_x_k(const void* __restrict__ xin, ushort_t* __restrict__ xb,
                            const int* __restrict__ flag) {
    size_t i = ((size_t)blockIdx.x * 256 + threadIdx.x) * 8;
    if (*flag) {
        *(short8*)&xb[i] = *(const short8*)((const ushort_t*)xin + i);
    } else {
        const float* xf = (const float*)xin + i;
        float4 a = *(const float4*)xf;
        float4 b = *(const float4*)(xf + 4);
        short8 o;
        o[0] = (short)f2bf(a.x); o[1] = (short)f2bf(a.y);
        o[2] = (short)f2bf(a.z); o[3] = (short)f2bf(a.w);
        o[4] = (short)f2bf(b.x); o[5] = (short)f2bf(b.y);
        o[6] = (short)f2bf(b.z); o[7] = (short)f2bf(b.w);
        *(short8*)&xb[i] = o;
    }
}

// ---------------- transpose(+convert): in[R][Nc] -> out[Nc][R] bf16 ----------------
__global__ void transpose_k(const void* __restrict__ in, ushort_t* __restrict__ out,
                            int R, int Nc, const int* __restrict__ flag) {
    __shared__ ushort_t t[32][33];
    int fl = *flag;
    const float* inf_ = (const float*)in;
    const ushort_t* inb = (const ushort_t*)in;
    int bc = blockIdx.x * 32;
    int br = blockIdx.y * 32;
    int lx = threadIdx.x & 31, ly = threadIdx.x >> 5;
#pragma unroll
    for (int i = 0; i < 4; ++i) {
        int r = ly + i * 8;
        size_t idx = (size_t)(br + r) * Nc + bc + lx;
        t[r][lx] = fl ? inb[idx] : f2bf(inf_[idx]);
    }
    __syncthreads();
#pragma unroll
    for (int i = 0; i < 4; ++i) {
        int r = ly + i * 8;
        out[(size_t)(bc + r) * R + br + lx] = t[lx][r];
    }
}

// ---------------- GEMM: C[M][N] = A[M][K] * Bt[N][K] + bias[N] ----------------
// MODE 0: write Cout[M][N] (fp32 or bf16 per flag).
// MODE 1: QKV scatter: Q,K -> [B*H][T][D]; V -> TRANSPOSED [B*H][D][T].
template <int MODE>
__launch_bounds__(256)
__global__ void gemm_bt(const ushort_t* __restrict__ A, const ushort_t* __restrict__ Bt,
                        const void* __restrict__ bias, void* __restrict__ Cout,
                        ushort_t* __restrict__ Qo, ushort_t* __restrict__ Ko,
                        ushort_t* __restrict__ Vo, int M, int N, int K,
                        const int* __restrict__ flag) {
    __shared__ __align__(16) ushort_t Alds[128 * 32];
    __shared__ __align__(16) ushort_t Blds[128 * 32];
    int tid = threadIdx.x;
    int wave = tid >> 6, lane = tid & 63;
    int bm = blockIdx.x * 128, bn = blockIdx.y * 128;
    int wr = (wave >> 1) * 64, wc = (wave & 1) * 64;
    int lm = lane & 15, lk = (lane >> 4) * 8, lq = lane >> 4;

    floatx4 acc[4][4] = {};

    int srow = tid >> 2;
    int scol = (tid & 3) * 8;
    const ushort_t* Ab = A + (size_t)(bm + srow) * K + scol;
    const ushort_t* Bb = Bt + (size_t)(bn + srow) * K + scol;
    ushort_t* Al0 = &Alds[wave * 512];
    ushort_t* Al1 = &Alds[2048 + wave * 512];
    ushort_t* Bl0 = &Blds[wave * 512];
    ushort_t* Bl1 = &Blds[2048 + wave * 512];
    size_t rowskip = (size_t)64 * K;

    for (int k0 = 0; k0 < K; k0 += 32) {
        __syncthreads();
        gload16(Ab + k0, Al0);
        gload16(Ab + k0 + rowskip, Al1);
        gload16(Bb + k0, Bl0);
        gload16(Bb + k0 + rowskip, Bl1);
        __syncthreads();
        short8 af[4], bf[4];
#pragma unroll
        for (int i = 0; i < 4; ++i)
            af[i] = *(const short8*)&Alds[(wr + i * 16 + lm) * 32 + lk];
#pragma unroll
        for (int i = 0; i < 4; ++i)
            bf[i] = *(const short8*)&Blds[(wc + i * 16 + lm) * 32 + lk];
#pragma unroll
        for (int mi = 0; mi < 4; ++mi)
#pragma unroll
            for (int ni = 0; ni < 4; ++ni)
                acc[mi][ni] = __builtin_amdgcn_mfma_f32_16x16x32_bf16(
                    af[mi], bf[ni], acc[mi][ni], 0, 0, 0);
    }

    int fl = *flag;
#pragma unroll
    for (int mi = 0; mi < 4; ++mi) {
#pragma unroll
        for (int ni = 0; ni < 4; ++ni) {
            int col = bn + wc + ni * 16 + lm;
            float bv = fl ? bf2f(((const ushort_t*)bias)[col]) : ((const float*)bias)[col];
#pragma unroll
            for (int r = 0; r < 4; ++r) {
                int row = bm + wr + mi * 16 + lq * 4 + r;
                float v = acc[mi][ni][r] + bv;
                if (MODE == 0) {
                    if (fl) ((ushort_t*)Cout)[(size_t)row * N + col] = f2bf(v);
                    else    ((float*)Cout)[(size_t)row * N + col] = v;
                } else {
                    int b = row >> 11, t = row & (T_ - 1);
                    int which = col >> 10, c = col & (C_ - 1);
                    int h = c >> 6, d = c & 63;
                    ushort_t bb = f2bf(v);
                    int bh = b * H_ + h;
                    if (which == 0)
                        Qo[((size_t)bh * T_ + t) * D_ + d] = bb;
                    else if (which == 1)
                        Ko[((size_t)bh * T_ + t) * D_ + d] = bb;
                    else  // V stored transposed: [bh][d][t]
                        Vo[((size_t)bh * D_ + d) * T_ + t] = bb;
                }
            }
        }
    }
}

// ---------------- flash attention, causal ----------------
// grid: (T/128, B*H). Block: 256 = 4 waves; wave w owns Q rows [q0+32w, q0+32w+32).
// Q,K: [bh][T][D]; V: [bh][D][T] (pre-transposed). Output bf16 [B][T][C].
__launch_bounds__(256)
__global__ void attn_k(const ushort_t* __restrict__ Q, const ushort_t* __restrict__ K,
                       const ushort_t* __restrict__ Vt, ushort_t* __restrict__ O) {
    __shared__ __align__(16) ushort_t Klds[64 * 72];
    __shared__ __align__(16) ushort_t Vtlds[64 * 72];
    __shared__ __align__(16) ushort_t Plds[4][32 * 72];

    int tid = threadIdx.x, wave = tid >> 6, lane = tid & 63;
    int bh = blockIdx.y;
    int b = bh >> 4, h = bh & 15;
    int q0 = ((int)gridDim.x - 1 - (int)blockIdx.x) * 128;  // heavy blocks first
    int m0 = q0 + wave * 32;                                // wave's 32 Q rows
    int lm = lane & 15, lq = lane >> 4;

    const ushort_t* Qp = Q + (size_t)bh * T_ * D_;
    const ushort_t* Kp = K + (size_t)bh * T_ * D_;
    const ushort_t* Vp = Vt + (size_t)bh * D_ * T_;  // [d][t]

    // Q fragments: 2 m-tiles x 2 k-halves
    short8 qf[2][2];
#pragma unroll
    for (int mt = 0; mt < 2; ++mt)
#pragma unroll
        for (int kk = 0; kk < 2; ++kk)
            qf[mt][kk] = *(const short8*)&Qp[(size_t)(m0 + mt * 16 + lm) * D_ + kk * 32 + lq * 8];

    floatx4 oacc[2][4] = {};
    float mi_[2][4], li_[2][4];
#pragma unroll
    for (int mt = 0; mt < 2; ++mt)
#pragma unroll
        for (int r = 0; r < 4; ++r) { mi_[mt][r] = -__builtin_inff(); li_[mt][r] = 0.f; }

    int srow = tid >> 2;          // 0..63
    int scol = (tid & 3) * 16;    // 0,16,32,48

    int ntiles = q0 / 64 + 2;
    for (int it = 0; it < ntiles; ++it) {
        int kv0 = it * 64;
        __syncthreads();
        // stage K [kv][d] and Vt [d][kv], rows padded to 72; 2x short8 per thread each
        {
            const ushort_t* ks = &Kp[(size_t)(kv0 + srow) * D_ + scol];
            *(short8*)&Klds[srow * 72 + scol] = *(const short8*)ks;
            *(short8*)&Klds[srow * 72 + scol + 8] = *(const short8*)(ks + 8);
            const ushort_t* vs = &Vp[(size_t)srow * T_ + kv0 + scol];
            *(short8*)&Vtlds[srow * 72 + scol] = *(const short8*)vs;
            *(short8*)&Vtlds[srow * 72 + scol + 8] = *(const short8*)(vs + 8);
        }
        __syncthreads();
        if (kv0 > m0 + 31) continue;  // tile fully masked for this wave (barriers done)

        // K fragments (shared across both m-tiles)
        short8 kf[4][2];
#pragma unroll
        for (int nt = 0; nt < 4; ++nt)
#pragma unroll
            for (int kk = 0; kk < 2; ++kk)
                kf[nt][kk] = *(const short8*)&Klds[(nt * 16 + lm) * 72 + kk * 32 + lq * 8];

#pragma unroll
        for (int mt = 0; mt < 2; ++mt) {
            int mbase = m0 + mt * 16;
            floatx4 s[4] = {};
#pragma unroll
            for (int nt = 0; nt < 4; ++nt) {
                s[nt] = __builtin_amdgcn_mfma_f32_16x16x32_bf16(qf[mt][0], kf[nt][0], s[nt], 0, 0, 0);
                s[nt] = __builtin_amdgcn_mfma_f32_16x16x32_bf16(qf[mt][1], kf[nt][1], s[nt], 0, 0, 0);
            }
            if (kv0 + 63 > mbase) {  // tile straddles diagonal for this m-tile
#pragma unroll
                for (int nt = 0; nt < 4; ++nt)
#pragma unroll
                    for (int r = 0; r < 4; ++r) {
                        int colg = kv0 + nt * 16 + lm;
                        int rowg = mbase + lq * 4 + r;
                        if (colg > rowg) s[nt][r] = -__builtin_inff();
                    }
            }
            // online softmax for 4 rows
#pragma unroll
            for (int r = 0; r < 4; ++r) {
                float mx = fmaxf(fmaxf(s[0][r], s[1][r]), fmaxf(s[2][r], s[3][r]));
#pragma unroll
                for (int off = 1; off < 16; off <<= 1) mx = fmaxf(mx, __shfl_xor(mx, off));
                float mnew = fmaxf(mi_[mt][r], mx);
                float alpha = exp2f((mi_[mt][r] - mnew) * KSC);
                float rsum = 0.f;
#pragma unroll
                for (int nt = 0; nt < 4; ++nt) {
                    float p = exp2f((s[nt][r] - mnew) * KSC);
                    rsum += p;
                    Plds[wave][(mt * 16 + lq * 4 + r) * 72 + nt * 16 + lm] = f2bf(p);
                }
#pragma unroll
                for (int off = 1; off < 16; off <<= 1) rsum += __shfl_xor(rsum, off);
                li_[mt][r] = li_[mt][r] * alpha + rsum;
                mi_[mt][r] = mnew;
#pragma unroll
                for (int dt = 0; dt < 4; ++dt) oacc[mt][dt][r] *= alpha;
            }
        }

        asm volatile("s_waitcnt lgkmcnt(0)" ::: "memory");  // P writes -> P reads (same wave)

        // O += P V : V fragments shared across m-tiles
        short8 vf[4][2];
#pragma unroll
        for (int dt = 0; dt < 4; ++dt)
#pragma unroll
            for (int kk = 0; kk < 2; ++kk)
                vf[dt][kk] = *(const short8*)&Vtlds[(dt * 16 + lm) * 72 + kk * 32 + lq * 8];
#pragma unroll
        for (int mt = 0; mt < 2; ++mt) {
            short8 pf0 = *(const short8*)&Plds[wave][(mt * 16 + lm) * 72 + lq * 8];
            short8 pf1 = *(const short8*)&Plds[wave][(mt * 16 + lm) * 72 + 32 + lq * 8];
#pragma unroll
            for (int dt = 0; dt < 4; ++dt) {
                oacc[mt][dt] = __builtin_amdgcn_mfma_f32_16x16x32_bf16(pf0, vf[dt][0], oacc[mt][dt], 0, 0, 0);
                oacc[mt][dt] = __builtin_amdgcn_mfma_f32_16x16x32_bf16(pf1, vf[dt][1], oacc[mt][dt], 0, 0, 0);
            }
        }
    }

    // epilogue: O /= l, write bf16 to attn_out[b][t][h*64+d]
    ushort_t* Ob = O + ((size_t)b * T_) * C_ + h * D_;
#pragma unroll
    for (int mt = 0; mt < 2; ++mt)
#pragma unroll
        for (int r = 0; r < 4; ++r) {
            float inv = 1.0f / li_[mt][r];
            int rowg = m0 + mt * 16 + lq * 4 + r;
#pragma unroll
            for (int dt = 0; dt < 4; ++dt)
                Ob[(size_t)rowg * C_ + dt * 16 + lm] = f2bf(oacc[mt][dt][r] * inv);
        }
}

extern "C" void kernel_launch(void* const* d_in, const int* in_sizes, int n_in,
                              void* d_out, int out_size, void* d_ws, size_t ws_size,
                              hipStream_t stream) {
    const void* x    = d_in[0];
    const void* Wqkv = d_in[1];
    const void* bqkv = d_in[2];
    const void* Wo   = d_in[3];
    const void* bo   = d_in[4];

    int* flag = (int*)d_ws;
    ushort_t* ws = (ushort_t*)d_ws + 8;                    // 16B header
    ushort_t* WqkvT = ws;                                  // [3C][C] bf16
    ushort_t* WoT   = WqkvT + (size_t)N3C * C_;            // [C][C]  bf16
    ushort_t* Xb    = WoT + (size_t)C_ * C_;               // [BT][C] bf16
    ushort_t* Qs    = Xb + (size_t)BT_ * C_;               // [B*H][T][D] bf16
    ushort_t* Ks    = Qs + (size_t)BT_ * C_;               // [B*H][T][D]
    ushort_t* Vs    = Ks + (size_t)BT_ * C_;               // [B*H][D][T] (transposed)
    ushort_t* Attn  = Vs + (size_t)BT_ * C_;               // [B*T][C]

    detect_k<<<1, 64, 0, stream>>>((const float*)Wqkv, flag);
    convert_x_k<<<BT_ * C_ / (256 * 8), 256, 0, stream>>>(x, Xb, flag);
    transpose_k<<<dim3(N3C / 32, C_ / 32), 256, 0, stream>>>(Wqkv, WqkvT, C_, N3C, flag);
    transpose_k<<<dim3(C_ / 32, C_ / 32), 256, 0, stream>>>(Wo, WoT, C_, C_, flag);
    gemm_bt<1><<<dim3(BT_ / 128, N3C / 128), 256, 0, stream>>>(
        Xb, WqkvT, bqkv, nullptr, Qs, Ks, Vs, BT_, N3C, C_, flag);
    attn_k<<<dim3(T_ / 128, B_ * H_), 256, 0, stream>>>(Qs, Ks, Vs, Attn);
    gemm_bt<0><<<dim3(BT_ / 128, C_ / 128), 256, 0, stream>>>(
        Attn, WoT, bo, d_out, nullptr, nullptr, nullptr, BT_, C_, C_, flag);
}

// Round 5
// 477.706 us; speedup vs baseline: 1.1382x; 1.0463x over previous
//
#include <hip/hip_runtime.h>

typedef unsigned short ushort_t;
typedef __attribute__((ext_vector_type(8))) short short8;
typedef __attribute__((ext_vector_type(4))) float floatx4;

#define B_ 4
#define T_ 2048
#define C_ 1024
#define H_ 16
#define D_ 64
#define BT_ (B_ * T_)
#define N3C (3 * C_)

// softmax scale * log2(e): use exp2
#define KSC 0.18033688011112042f

__device__ __forceinline__ float bf2f(ushort_t h) {
    return __uint_as_float(((unsigned)h) << 16);
}
__device__ __forceinline__ ushort_t f2bf(float f) {
    unsigned u = __float_as_uint(f);
    u += 0x7FFF + ((u >> 16) & 1);  // round-nearest-even
    return (ushort_t)(u >> 16);
}
__device__ __forceinline__ unsigned pack2bf(float a, float b) {
    return (unsigned)f2bf(a) | ((unsigned)f2bf(b) << 16);
}

__device__ __forceinline__ void gload16(const ushort_t* g, ushort_t* l) {
    __builtin_amdgcn_global_load_lds((const __attribute__((address_space(1))) void*)g,
                                     (__attribute__((address_space(3))) void*)l, 16, 0, 0);
}

// ---------------- dtype probe: fp32 buffer -> |v| small; bf16 misread -> |v|~1e34/NaN ----
__global__ void detect_k(const float* __restrict__ w, int* __restrict__ flag) {
    float f = w[threadIdx.x];
    bool big = !(fabsf(f) <= 1e20f);
    unsigned long long m = __ballot(big);
    if (threadIdx.x == 0) flag[0] = (m != 0ull) ? 1 : 0;
}

// ---------------- x -> bf16 (convert or copy) ----------------
__global__ void convert_x_k(const void* __restrict__ xin, ushort_t* __restrict__ xb,
                            const int* __restrict__ flag) {
    size_t i = ((size_t)blockIdx.x * 256 + threadIdx.x) * 8;
    if (*flag) {
        *(short8*)&xb[i] = *(const short8*)((const ushort_t*)xin + i);
    } else {
        const float* xf = (const float*)xin + i;
        float4 a = *(const float4*)xf;
        float4 b = *(const float4*)(xf + 4);
        short8 o;
        o[0] = (short)f2bf(a.x); o[1] = (short)f2bf(a.y);
        o[2] = (short)f2bf(a.z); o[3] = (short)f2bf(a.w);
        o[4] = (short)f2bf(b.x); o[5] = (short)f2bf(b.y);
        o[6] = (short)f2bf(b.z); o[7] = (short)f2bf(b.w);
        *(short8*)&xb[i] = o;
    }
}

// ---------------- transpose(+convert): in[R][Nc] -> out[Nc][R] bf16 ----------------
__global__ void transpose_k(const void* __restrict__ in, ushort_t* __restrict__ out,
                            int R, int Nc, const int* __restrict__ flag) {
    __shared__ ushort_t t[32][33];
    int fl = *flag;
    const float* inf_ = (const float*)in;
    const ushort_t* inb = (const ushort_t*)in;
    int bc = blockIdx.x * 32;
    int br = blockIdx.y * 32;
    int lx = threadIdx.x & 31, ly = threadIdx.x >> 5;
#pragma unroll
    for (int i = 0; i < 4; ++i) {
        int r = ly + i * 8;
        size_t idx = (size_t)(br + r) * Nc + bc + lx;
        t[r][lx] = fl ? inb[idx] : f2bf(inf_[idx]);
    }
    __syncthreads();
#pragma unroll
    for (int i = 0; i < 4; ++i) {
        int r = ly + i * 8;
        out[(size_t)(bc + r) * R + br + lx] = t[lx][r];
    }
}

// ---------------- GEMM: C[M][N] = A[M][K] * Bt[N][K] + bias[N] ----------------
// MODE 0: write Cout[M][N] (fp32 or bf16 per flag).
// MODE 1: QKV scatter: Q,K -> [B*H][T][D]; V -> TRANSPOSED [B*H][D][T].
template <int MODE>
__launch_bounds__(256)
__global__ void gemm_bt(const ushort_t* __restrict__ A, const ushort_t* __restrict__ Bt,
                        const void* __restrict__ bias, void* __restrict__ Cout,
                        ushort_t* __restrict__ Qo, ushort_t* __restrict__ Ko,
                        ushort_t* __restrict__ Vo, int M, int N, int K,
                        const int* __restrict__ flag) {
    __shared__ __align__(16) ushort_t Alds[128 * 32];
    __shared__ __align__(16) ushort_t Blds[128 * 32];
    int tid = threadIdx.x;
    int wave = tid >> 6, lane = tid & 63;
    int bm = blockIdx.x * 128, bn = blockIdx.y * 128;
    int wr = (wave >> 1) * 64, wc = (wave & 1) * 64;
    int lm = lane & 15, lk = (lane >> 4) * 8, lq = lane >> 4;

    floatx4 acc[4][4] = {};

    int srow = tid >> 2;
    int scol = (tid & 3) * 8;
    const ushort_t* Ab = A + (size_t)(bm + srow) * K + scol;
    const ushort_t* Bb = Bt + (size_t)(bn + srow) * K + scol;
    ushort_t* Al0 = &Alds[wave * 512];
    ushort_t* Al1 = &Alds[2048 + wave * 512];
    ushort_t* Bl0 = &Blds[wave * 512];
    ushort_t* Bl1 = &Blds[2048 + wave * 512];
    size_t rowskip = (size_t)64 * K;

    for (int k0 = 0; k0 < K; k0 += 32) {
        __syncthreads();
        gload16(Ab + k0, Al0);
        gload16(Ab + k0 + rowskip, Al1);
        gload16(Bb + k0, Bl0);
        gload16(Bb + k0 + rowskip, Bl1);
        __syncthreads();
        short8 af[4], bf[4];
#pragma unroll
        for (int i = 0; i < 4; ++i)
            af[i] = *(const short8*)&Alds[(wr + i * 16 + lm) * 32 + lk];
#pragma unroll
        for (int i = 0; i < 4; ++i)
            bf[i] = *(const short8*)&Blds[(wc + i * 16 + lm) * 32 + lk];
#pragma unroll
        for (int mi = 0; mi < 4; ++mi)
#pragma unroll
            for (int ni = 0; ni < 4; ++ni)
                acc[mi][ni] = __builtin_amdgcn_mfma_f32_16x16x32_bf16(
                    af[mi], bf[ni], acc[mi][ni], 0, 0, 0);
    }

    int fl = *flag;
#pragma unroll
    for (int mi = 0; mi < 4; ++mi) {
#pragma unroll
        for (int ni = 0; ni < 4; ++ni) {
            int col = bn + wc + ni * 16 + lm;
            float bv = fl ? bf2f(((const ushort_t*)bias)[col]) : ((const float*)bias)[col];
#pragma unroll
            for (int r = 0; r < 4; ++r) {
                int row = bm + wr + mi * 16 + lq * 4 + r;
                float v = acc[mi][ni][r] + bv;
                if (MODE == 0) {
                    if (fl) ((ushort_t*)Cout)[(size_t)row * N + col] = f2bf(v);
                    else    ((float*)Cout)[(size_t)row * N + col] = v;
                } else {
                    int b = row >> 11, t = row & (T_ - 1);
                    int which = col >> 10, c = col & (C_ - 1);
                    int h = c >> 6, d = c & 63;
                    ushort_t bb = f2bf(v);
                    int bh = b * H_ + h;
                    if (which == 0)
                        Qo[((size_t)bh * T_ + t) * D_ + d] = bb;
                    else if (which == 1)
                        Ko[((size_t)bh * T_ + t) * D_ + d] = bb;
                    else  // V stored transposed: [bh][d][t]
                        Vo[((size_t)bh * D_ + d) * T_ + t] = bb;
                }
            }
        }
    }
}

// ---------------- flash attention, causal, S^T/O^T formulation ----------------
// grid: (T/128, B*H). Block 256 = 4 waves; wave w owns 32 Q rows [q0+32w, q0+32w+32).
// Q,K: [bh][T][D]; V: [bh][D][T] (pre-transposed). No __syncthreads: K/V fragments
// load straight from global (L1-resident tiles); LDS used only for the per-wave
// P round-trip (C-layout -> B-operand layout).
__launch_bounds__(256)
__global__ void attn_k(const ushort_t* __restrict__ Q, const ushort_t* __restrict__ K,
                       const ushort_t* __restrict__ Vt, ushort_t* __restrict__ O) {
    __shared__ __align__(16) ushort_t Plds[4][32 * 72];

    int tid = threadIdx.x, wave = tid >> 6, lane = tid & 63;
    int bh = blockIdx.y;
    int b = bh >> 4, h = bh & 15;
    int q0 = ((int)gridDim.x - 1 - (int)blockIdx.x) * 128;  // heavy blocks first
    int m0 = q0 + wave * 32;                                // wave's 32 Q rows
    int lm = lane & 15, lq = lane >> 4;

    const ushort_t* Qp = Q + (size_t)bh * T_ * D_;
    const ushort_t* Kp = K + (size_t)bh * T_ * D_;
    const ushort_t* Vp = Vt + (size_t)bh * D_ * T_;  // [d][t]
    ushort_t* Pw = &Plds[wave][0];                   // wave-private [32][72]

    // Q fragments (B-operand for S^T = K·Q^T): rows m, k = d
    short8 qf[2][2];
#pragma unroll
    for (int mt = 0; mt < 2; ++mt)
#pragma unroll
        for (int kk = 0; kk < 2; ++kk)
            qf[mt][kk] = *(const short8*)&Qp[(size_t)(m0 + mt * 16 + lm) * D_ + kk * 32 + lq * 8];

    floatx4 oacc[2][4] = {};                 // O^T: col m = lane&15, rows d
    float mi_[2] = {-__builtin_inff(), -__builtin_inff()};
    float li_[2] = {0.f, 0.f};

    int ntw = (m0 + 31) / 64 + 1;            // tiles with kv0 <= m0+31
    for (int it = 0; it < ntw; ++it) {
        int kv0 = it * 64;

        // K fragments (A-operand: rows kv, k = d) — direct global
        short8 kf[4][2];
#pragma unroll
        for (int nt = 0; nt < 4; ++nt)
#pragma unroll
            for (int kk = 0; kk < 2; ++kk)
                kf[nt][kk] = *(const short8*)&Kp[(size_t)(kv0 + nt * 16 + lm) * D_ + kk * 32 + lq * 8];
        // V^T fragments (A-operand for O^T: rows d, k = kv) — direct global
        short8 vf[4][2];
#pragma unroll
        for (int dt = 0; dt < 4; ++dt)
#pragma unroll
            for (int kk = 0; kk < 2; ++kk)
                vf[dt][kk] = *(const short8*)&Vp[(size_t)(dt * 16 + lm) * T_ + kv0 + kk * 32 + lq * 8];

        // S^T = K Q^T : col = m (lane&15), row = kv (lq*4+r)
        floatx4 st[2][4] = {};
#pragma unroll
        for (int mt = 0; mt < 2; ++mt)
#pragma unroll
            for (int nt = 0; nt < 4; ++nt) {
                st[mt][nt] = __builtin_amdgcn_mfma_f32_16x16x32_bf16(kf[nt][0], qf[mt][0], st[mt][nt], 0, 0, 0);
                st[mt][nt] = __builtin_amdgcn_mfma_f32_16x16x32_bf16(kf[nt][1], qf[mt][1], st[mt][nt], 0, 0, 0);
            }

        // causal mask (wave-uniform branch; normally only the last tile)
        if (kv0 + 63 > m0) {
#pragma unroll
            for (int mt = 0; mt < 2; ++mt) {
                int mg = m0 + mt * 16 + lm;
#pragma unroll
                for (int nt = 0; nt < 4; ++nt)
#pragma unroll
                    for (int r = 0; r < 4; ++r) {
                        int kvg = kv0 + nt * 16 + lq * 4 + r;
                        if (kvg > mg) st[mt][nt][r] = -__builtin_inff();
                    }
            }
        }

        // online softmax: KV dim is (regs x lq) -> in-reg reduce + 2 shuffles
#pragma unroll
        for (int mt = 0; mt < 2; ++mt) {
            float mx = st[mt][0][0];
#pragma unroll
            for (int nt = 0; nt < 4; ++nt)
#pragma unroll
                for (int r = 0; r < 4; ++r) mx = fmaxf(mx, st[mt][nt][r]);
            mx = fmaxf(mx, __shfl_xor(mx, 16));
            mx = fmaxf(mx, __shfl_xor(mx, 32));
            float mnew = fmaxf(mi_[mt], mx);
            float alpha = exp2f((mi_[mt] - mnew) * KSC);
            float sum = 0.f;
            int prow = (mt * 16 + lm) * 72 + lq * 4;
#pragma unroll
            for (int nt = 0; nt < 4; ++nt) {
                float p0 = exp2f((st[mt][nt][0] - mnew) * KSC);
                float p1 = exp2f((st[mt][nt][1] - mnew) * KSC);
                float p2 = exp2f((st[mt][nt][2] - mnew) * KSC);
                float p3 = exp2f((st[mt][nt][3] - mnew) * KSC);
                sum += (p0 + p1) + (p2 + p3);
                uint2 pk;
                pk.x = pack2bf(p0, p1);
                pk.y = pack2bf(p2, p3);
                *(uint2*)&Pw[prow + nt * 16] = pk;   // P[m][kv], 4 consecutive kv
            }
            sum += __shfl_xor(sum, 16);
            sum += __shfl_xor(sum, 32);
            li_[mt] = li_[mt] * alpha + sum;
            mi_[mt] = mnew;
#pragma unroll
            for (int dt = 0; dt < 4; ++dt) oacc[mt][dt] *= alpha;  // alpha lives at lane&15=m: direct
        }

        asm volatile("s_waitcnt lgkmcnt(0)" ::: "memory");  // P writes -> P reads (same wave)

        // O^T += V^T P^T : B-operand = P rows (n = m = lane&15, k = kv)
#pragma unroll
        for (int mt = 0; mt < 2; ++mt) {
            short8 pb0 = *(const short8*)&Pw[(mt * 16 + lm) * 72 + lq * 8];
            short8 pb1 = *(const short8*)&Pw[(mt * 16 + lm) * 72 + 32 + lq * 8];
#pragma unroll
            for (int dt = 0; dt < 4; ++dt) {
                oacc[mt][dt] = __builtin_amdgcn_mfma_f32_16x16x32_bf16(vf[dt][0], pb0, oacc[mt][dt], 0, 0, 0);
                oacc[mt][dt] = __builtin_amdgcn_mfma_f32_16x16x32_bf16(vf[dt][1], pb1, oacc[mt][dt], 0, 0, 0);
            }
        }
    }

    // epilogue: O^T col m = lane&15 -> row t; rows d = dt*16+lq*4+r -> packed 8B stores
    ushort_t* Ob = O + ((size_t)b * T_) * C_ + h * D_;
#pragma unroll
    for (int mt = 0; mt < 2; ++mt) {
        float inv = 1.0f / li_[mt];
        int tg = m0 + mt * 16 + lm;
#pragma unroll
        for (int dt = 0; dt < 4; ++dt) {
            uint2 pk;
            pk.x = pack2bf(oacc[mt][dt][0] * inv, oacc[mt][dt][1] * inv);
            pk.y = pack2bf(oacc[mt][dt][2] * inv, oacc[mt][dt][3] * inv);
            *(uint2*)&Ob[(size_t)tg * C_ + dt * 16 + lq * 4] = pk;
        }
    }
}

extern "C" void kernel_launch(void* const* d_in, const int* in_sizes, int n_in,
                              void* d_out, int out_size, void* d_ws, size_t ws_size,
                              hipStream_t stream) {
    const void* x    = d_in[0];
    const void* Wqkv = d_in[1];
    const void* bqkv = d_in[2];
    const void* Wo   = d_in[3];
    const void* bo   = d_in[4];

    int* flag = (int*)d_ws;
    ushort_t* ws = (ushort_t*)d_ws + 8;                    // 16B header
    ushort_t* WqkvT = ws;                                  // [3C][C] bf16
    ushort_t* WoT   = WqkvT + (size_t)N3C * C_;            // [C][C]  bf16
    ushort_t* Xb    = WoT + (size_t)C_ * C_;               // [BT][C] bf16
    ushort_t* Qs    = Xb + (size_t)BT_ * C_;               // [B*H][T][D] bf16
    ushort_t* Ks    = Qs + (size_t)BT_ * C_;               // [B*H][T][D]
    ushort_t* Vs    = Ks + (size_t)BT_ * C_;               // [B*H][D][T] (transposed)
    ushort_t* Attn  = Vs + (size_t)BT_ * C_;               // [B*T][C]

    detect_k<<<1, 64, 0, stream>>>((const float*)Wqkv, flag);
    convert_x_k<<<BT_ * C_ / (256 * 8), 256, 0, stream>>>(x, Xb, flag);
    transpose_k<<<dim3(N3C / 32, C_ / 32), 256, 0, stream>>>(Wqkv, WqkvT, C_, N3C, flag);
    transpose_k<<<dim3(C_ / 32, C_ / 32), 256, 0, stream>>>(Wo, WoT, C_, C_, flag);
    gemm_bt<1><<<dim3(BT_ / 128, N3C / 128), 256, 0, stream>>>(
        Xb, WqkvT, bqkv, nullptr, Qs, Ks, Vs, BT_, N3C, C_, flag);
    attn_k<<<dim3(T_ / 128, B_ * H_), 256, 0, stream>>>(Qs, Ks, Vs, Attn);
    gemm_bt<0><<<dim3(BT_ / 128, C_ / 128), 256, 0, stream>>>(
        Attn, WoT, bo, d_out, nullptr, nullptr, nullptr, BT_, C_, C_, flag);
}